// Round 12
// baseline (101.253 us; speedup 1.0000x reference)
//
#include <hip/hip_runtime.h>
#include <math.h>

#define B_ 8
#define C_ 128
#define N_ 64
#define T_ 512
#define H_ 4
#define D_ 32
#define OUT_ 128
#define E_ 256
#define EP_ 320   // E + N self-loops
#define NEG_SLOPE 0.2f
#define BN_EPS 1e-5f
#define NT_ (N_ * T_)

__device__ inline unsigned short f2bf(float f) {   // RNE float->bf16
  unsigned u = __float_as_uint(f);
  u += 0x7FFFu + ((u >> 16) & 1u);
  return (unsigned short)(u >> 16);
}
__device__ inline float bf2f(unsigned short s) {
  return __uint_as_float(((unsigned)s) << 16);
}

// ---- setup: wa[c][8] = W·att; in-list (src per in-edge, grouped by dst);
// ----        out-list (dst per out-edge, grouped by src)
__global__ void setup_kernel(const float* __restrict__ W,
                             const float* __restrict__ att_src,
                             const float* __restrict__ att_dst,
                             const int* __restrict__ edge_index,
                             float* __restrict__ wa,
                             int* __restrict__ iOff_g, int* __restrict__ iSrc_g,
                             int* __restrict__ oOff_g, int* __restrict__ oDst_g) {
  __shared__ int icnt[N_], ibase[N_ + 1], ifill[N_];
  __shared__ int ocnt[N_], obase[N_ + 1], ofill[N_];
  __shared__ int esrc[EP_], edst[EP_];
  int tid = threadIdx.x;

  for (int idx = tid; idx < C_ * 8; idx += blockDim.x) {
    int c = idx >> 3, j = idx & 7, h = j & 3;
    const float* att = (j < 4) ? att_src : att_dst;
    float s = 0.f;
    for (int d = 0; d < D_; ++d)
      s += W[(c * H_ + h) * D_ + d] * att[h * D_ + d];
    wa[idx] = s;
  }
  if (tid < N_) { icnt[tid] = 0; ifill[tid] = 0; ocnt[tid] = 0; ofill[tid] = 0; }
  __syncthreads();
  for (int e = tid; e < EP_; e += blockDim.x) {
    int s, d;
    if (e < E_) { s = edge_index[e]; d = edge_index[E_ + e]; }
    else        { s = e - E_;        d = e - E_; }
    esrc[e] = s; edst[e] = d;
    atomicAdd(&icnt[d], 1);
    atomicAdd(&ocnt[s], 1);
  }
  __syncthreads();
  if (tid == 0) {
    int ai = 0, ao = 0;
    for (int n = 0; n < N_; ++n) {
      ibase[n] = ai; ai += icnt[n];
      obase[n] = ao; ao += ocnt[n];
    }
    ibase[N_] = ai; obase[N_] = ao;
  }
  __syncthreads();
  if (tid <= N_) { iOff_g[tid] = ibase[tid]; oOff_g[tid] = obase[tid]; }
  for (int e = tid; e < EP_; e += blockDim.x) {
    int s = esrc[e], d = edst[e];
    int pi = ibase[d] + atomicAdd(&ifill[d], 1);
    iSrc_g[pi] = s;
    int po = obase[s] + atomicAdd(&ofill[s], 1);
    oDst_g[po] = d;
  }
}

// ---- K1: proj + bf16 transposed stage ------------------------------------------
// grid = 1024 (b = bid&7 XCD-pinned, n, t-half), block 256, 4 blocks/CU.
// Reads x in 1-KB contiguous (c,n)-rows; writes a_ws and xs[b][tc][c][n][t16] bf16.
__global__ __launch_bounds__(256, 4)
void proj_kernel(const float* __restrict__ x,
                 const float* __restrict__ wa_g,
                 float* __restrict__ a_ws,
                 unsigned short* __restrict__ xs) {
  __shared__ float wal[C_ * 8];
  __shared__ float4 red4[4 * 8 * 64];   // [cg][j][tq]  32 KB
  const int tid = threadIdx.x;
  const int bid = blockIdx.x;
  const int b = bid & 7;
  const int n = (bid >> 3) & 63;
  const int th = bid >> 9;

  for (int i = tid; i < C_ * 8; i += 256) wal[i] = wa_g[i];
  __syncthreads();

  const int cg = tid >> 6, tq = tid & 63;
  const int tc = th * 16 + (tq >> 2);      // 16-t tile index
  const int tl = (tq & 3) * 4;             // offset within tile
  const float* xp = x + ((size_t)(b * C_) * N_ + n) * T_ + th * 256 + tq * 4;
  unsigned short* xsb = xs + ((size_t)(b * 32 + tc) * 128) * 1024 + n * 16 + tl;

  float4 acc[8];
#pragma unroll
  for (int j = 0; j < 8; ++j) { acc[j].x = 0.f; acc[j].y = 0.f; acc[j].z = 0.f; acc[j].w = 0.f; }
  for (int kb = 0; kb < 8; ++kb) {
    float4 xv[4];
#pragma unroll
    for (int u = 0; u < 4; ++u) {
      int c = cg + (kb * 4 + u) * 4;
      xv[u] = *reinterpret_cast<const float4*>(xp + (size_t)c * NT_);
    }
#pragma unroll
    for (int u = 0; u < 4; ++u) {
      int c = cg + (kb * 4 + u) * 4;
      ushort4 s;
      s.x = f2bf(xv[u].x); s.y = f2bf(xv[u].y);
      s.z = f2bf(xv[u].z); s.w = f2bf(xv[u].w);
      *reinterpret_cast<ushort4*>(xsb + (size_t)c * 1024) = s;
#pragma unroll
      for (int j = 0; j < 8; ++j) {
        float wj = wal[c * 8 + j];
        acc[j].x = fmaf(xv[u].x, wj, acc[j].x);
        acc[j].y = fmaf(xv[u].y, wj, acc[j].y);
        acc[j].z = fmaf(xv[u].z, wj, acc[j].z);
        acc[j].w = fmaf(xv[u].w, wj, acc[j].w);
      }
    }
  }
#pragma unroll
  for (int j = 0; j < 8; ++j) red4[(cg * 8 + j) * 64 + tq] = acc[j];
  __syncthreads();

#pragma unroll
  for (int rep = 0; rep < 2; ++rep) {
    int ss = tid + rep * 256;
    int j = ss >> 6, tq2 = ss & 63;
    float4 v0 = red4[(0 * 8 + j) * 64 + tq2];
    float4 v1 = red4[(1 * 8 + j) * 64 + tq2];
    float4 v2 = red4[(2 * 8 + j) * 64 + tq2];
    float4 v3 = red4[(3 * 8 + j) * 64 + tq2];
    float4 r;
    r.x = (v0.x + v1.x) + (v2.x + v3.x);
    r.y = (v0.y + v1.y) + (v2.y + v3.y);
    r.z = (v0.z + v1.z) + (v2.z + v3.z);
    r.w = (v0.w + v1.w) + (v2.w + v3.w);
    *reinterpret_cast<float4*>(
        a_ws + ((size_t)(b * N_ + n) * 8 + j) * T_ + th * 256 + tq2 * 4) = r;
  }
}

// ---- K2: softmax + aggregation (contiguous bf16 tile stream) + epilogue --------
// grid = 256 (b = bid&7, tc = bid>>3), block 512, 1 block/CU.
__global__ __launch_bounds__(512, 1)
void agg_kernel(const unsigned short* __restrict__ xs,
                const float* __restrict__ a_ws,
                const float* __restrict__ Wm,
                const int* __restrict__ iOff_g, const int* __restrict__ iSrc_g,
                const int* __restrict__ oOff_g, const int* __restrict__ oDst_g,
                const float* __restrict__ bias,
                const float* __restrict__ bn_gamma,
                const float* __restrict__ bn_beta,
                const float* __restrict__ bn_mean,
                const float* __restrict__ bn_var,
                float* __restrict__ out) {
  __shared__ __align__(16) char arena[76816];
  float* a_l  = (float*)arena;                      // [8j][64n][20] 40960 B (softmax)
  float* z_l  = (float*)(arena + 40960);            // [64nd][16t][4h] 16 KB
  float* w_l  = (float*)(arena + 57344);            // [n*64 + h*16 + t] 16 KB
  unsigned short* xst = (unsigned short*)arena;     // overlay: [16c][64n][16t] 32 KB
  float* scr  = (float*)(arena + 32768);            // [16c][16t][4h] 4 KB
  float* yoct = (float*)(arena + 36864);            // [4h][16c][17] 4352 B
  int* iSrc = (int*)(arena + 73728);
  int* oDst = iSrc + EP_;
  int* iOff = oDst + EP_;
  int* oOff = iOff + (N_ + 1);

  const int tid = threadIdx.x;
  const int b  = blockIdx.x & 7;
  const int tc = blockIdx.x >> 3;
  const int t0 = tc * 16;

  if (tid < EP_) { iSrc[tid] = iSrc_g[tid]; oDst[tid] = oDst_g[tid]; }
  else if (tid < EP_ + N_ + 1) {
    int i = tid - EP_;
    iOff[i] = iOff_g[i]; oOff[i] = oOff_g[i];
  }
  {  // a_l load: 512 rows (n,j) of 16 floats
    int n = tid >> 3, j = tid & 7;
    const float4* src = reinterpret_cast<const float4*>(
        a_ws + (((size_t)b * N_ + n) * 8 + j) * T_ + t0);
    float4* dst = reinterpret_cast<float4*>(&a_l[j * 1280 + n * 20]);
    dst[0] = src[0]; dst[1] = src[1]; dst[2] = src[2]; dst[3] = src[3];
  }
  __syncthreads();

  // softmax B: per (dst,t): z = exp(-m)/(den*N)
  {
    const int t = tid & 15, g = tid >> 4;
#pragma unroll
    for (int rep = 0; rep < 2; ++rep) {
      int nd = g + rep * 32;
      int e0 = iOff[nd], e1 = iOff[nd + 1];
      float ad0 = a_l[4 * 1280 + nd * 20 + t];
      float ad1 = a_l[5 * 1280 + nd * 20 + t];
      float ad2 = a_l[6 * 1280 + nd * 20 + t];
      float ad3 = a_l[7 * 1280 + nd * 20 + t];
      float m0 = -1e30f, m1 = -1e30f, m2 = -1e30f, m3 = -1e30f;
      for (int e = e0; e < e1; ++e) {
        int s = iSrc[e];
        float v0 = a_l[0 * 1280 + s * 20 + t] + ad0; v0 = v0 > 0.f ? v0 : NEG_SLOPE * v0;
        float v1 = a_l[1 * 1280 + s * 20 + t] + ad1; v1 = v1 > 0.f ? v1 : NEG_SLOPE * v1;
        float v2 = a_l[2 * 1280 + s * 20 + t] + ad2; v2 = v2 > 0.f ? v2 : NEG_SLOPE * v2;
        float v3 = a_l[3 * 1280 + s * 20 + t] + ad3; v3 = v3 > 0.f ? v3 : NEG_SLOPE * v3;
        m0 = fmaxf(m0, v0); m1 = fmaxf(m1, v1);
        m2 = fmaxf(m2, v2); m3 = fmaxf(m3, v3);
      }
      float d0 = 0.f, d1 = 0.f, d2 = 0.f, d3 = 0.f;
      for (int e = e0; e < e1; ++e) {
        int s = iSrc[e];
        float v0 = a_l[0 * 1280 + s * 20 + t] + ad0; v0 = v0 > 0.f ? v0 : NEG_SLOPE * v0;
        float v1 = a_l[1 * 1280 + s * 20 + t] + ad1; v1 = v1 > 0.f ? v1 : NEG_SLOPE * v1;
        float v2 = a_l[2 * 1280 + s * 20 + t] + ad2; v2 = v2 > 0.f ? v2 : NEG_SLOPE * v2;
        float v3 = a_l[3 * 1280 + s * 20 + t] + ad3; v3 = v3 > 0.f ? v3 : NEG_SLOPE * v3;
        d0 += __expf(v0 - m0); d1 += __expf(v1 - m1);
        d2 += __expf(v2 - m2); d3 += __expf(v3 - m3);
      }
      float4 zv;
      zv.x = __expf(-m0) / (d0 * (float)N_);
      zv.y = __expf(-m1) / (d1 * (float)N_);
      zv.z = __expf(-m2) / (d2 * (float)N_);
      zv.w = __expf(-m3) / (d3 * (float)N_);
      *reinterpret_cast<float4*>(&z_l[(nd * 16 + t) * 4]) = zv;
    }
  }
  __syncthreads();

  // softmax C: per (src,t) gather -> w_l[n*64 + h*16 + t]
  {
    const int t = tid & 15, g = tid >> 4;
#pragma unroll
    for (int rep = 0; rep < 2; ++rep) {
      int src = g + rep * 32;
      int e0 = oOff[src], e1 = oOff[src + 1];
      float as0 = a_l[0 * 1280 + src * 20 + t];
      float as1 = a_l[1 * 1280 + src * 20 + t];
      float as2 = a_l[2 * 1280 + src * 20 + t];
      float as3 = a_l[3 * 1280 + src * 20 + t];
      float w0 = 0.f, w1 = 0.f, w2 = 0.f, w3 = 0.f;
      for (int e = e0; e < e1; ++e) {
        int d = oDst[e];
        float4 zv = *reinterpret_cast<const float4*>(&z_l[(d * 16 + t) * 4]);
        float v0 = as0 + a_l[4 * 1280 + d * 20 + t]; v0 = v0 > 0.f ? v0 : NEG_SLOPE * v0;
        float v1 = as1 + a_l[5 * 1280 + d * 20 + t]; v1 = v1 > 0.f ? v1 : NEG_SLOPE * v1;
        float v2 = as2 + a_l[6 * 1280 + d * 20 + t]; v2 = v2 > 0.f ? v2 : NEG_SLOPE * v2;
        float v3 = as3 + a_l[7 * 1280 + d * 20 + t]; v3 = v3 > 0.f ? v3 : NEG_SLOPE * v3;
        w0 += __expf(v0) * zv.x;
        w1 += __expf(v1) * zv.y;
        w2 += __expf(v2) * zv.z;
        w3 += __expf(v3) * zv.w;
      }
      w_l[src * 64 +  0 + t] = w0;
      w_l[src * 64 + 16 + t] = w1;
      w_l[src * 64 + 32 + t] = w2;
      w_l[src * 64 + 48 + t] = w3;
    }
  }
  __syncthreads();

  // aggregation + fused epilogue: 8 octs of 16 c
  const int cl = tid >> 5;            // compute: c-local 0..15
  const int tt = (tid >> 1) & 15;
  const int nh = tid & 1;
  const int h4 = tid >> 7;            // epilogue: head
  const int dp = (tid >> 4) & 7;      // d-group (4 d's)
  const int te = tid & 15;
  float oacc[4] = {0.f, 0.f, 0.f, 0.f};
  const uint4* xtile = reinterpret_cast<const uint4*>(
      xs + ((size_t)(b * 32 + tc) * 128) * 1024);

  for (int o = 0; o < 8; ++o) {
    // stage 16-c chunk (32 KB) contiguous
    {
      const uint4* src = xtile + (size_t)o * 2048;
      uint4* dst = reinterpret_cast<uint4*>(xst);
#pragma unroll
      for (int i = 0; i < 4; ++i) dst[tid + 512 * i] = src[tid + 512 * i];
    }
    __syncthreads();
    // compute y[h] for (c = o*16+cl, t = tt), n-half nh
    {
      float y0 = 0.f, y1 = 0.f, y2 = 0.f, y3 = 0.f;
#pragma unroll 8
      for (int i = 0; i < 32; ++i) {
        int n = nh * 32 + i;
        float xv = bf2f(xst[cl * 1024 + n * 16 + tt]);
        y0 = fmaf(xv, w_l[n * 64 +  0 + tt], y0);
        y1 = fmaf(xv, w_l[n * 64 + 16 + tt], y1);
        y2 = fmaf(xv, w_l[n * 64 + 32 + tt], y2);
        y3 = fmaf(xv, w_l[n * 64 + 48 + tt], y3);
      }
      if (nh) {
        float4 v; v.x = y0; v.y = y1; v.z = y2; v.w = y3;
        *reinterpret_cast<float4*>(&scr[(cl * 16 + tt) * 4]) = v;
      }
      __syncthreads();
      if (!nh) {
        float4 v = *reinterpret_cast<const float4*>(&scr[(cl * 16 + tt) * 4]);
        yoct[0 * 272 + cl * 17 + tt] = y0 + v.x;
        yoct[1 * 272 + cl * 17 + tt] = y1 + v.y;
        yoct[2 * 272 + cl * 17 + tt] = y2 + v.z;
        yoct[3 * 272 + cl * 17 + tt] = y3 + v.w;
      }
    }
    __syncthreads();
    // epilogue partial: oacc += y_oct · W   (thread = (h4, dp, te))
    {
#pragma unroll 4
      for (int i = 0; i < 16; ++i) {
        int c = o * 16 + i;
        float yv = yoct[h4 * 272 + i * 17 + te];
        const float4 wv = *reinterpret_cast<const float4*>(
            &Wm[((size_t)c * H_ + h4) * D_ + dp * 4]);
        oacc[0] = fmaf(yv, wv.x, oacc[0]);
        oacc[1] = fmaf(yv, wv.y, oacc[1]);
        oacc[2] = fmaf(yv, wv.z, oacc[2]);
        oacc[3] = fmaf(yv, wv.w, oacc[3]);
      }
    }
    __syncthreads();
  }

  // final: bias + BN -> out
#pragma unroll
  for (int k = 0; k < 4; ++k) {
    int oc = h4 * D_ + dp * 4 + k;
    float scale = bn_gamma[oc] * rsqrtf(bn_var[oc] + BN_EPS);
    float shift = bn_beta[oc] - bn_mean[oc] * scale;
    out[((size_t)b * OUT_ + oc) * T_ + t0 + te] =
        (oacc[k] + bias[oc]) * scale + shift;
  }
}

extern "C" void kernel_launch(void* const* d_in, const int* in_sizes, int n_in,
                              void* d_out, int out_size, void* d_ws, size_t ws_size,
                              hipStream_t stream) {
  const float* x        = (const float*)d_in[0];
  const float* W        = (const float*)d_in[1];
  const float* att_src  = (const float*)d_in[2];
  const float* att_dst  = (const float*)d_in[3];
  const float* bias     = (const float*)d_in[4];
  const float* bn_gamma = (const float*)d_in[5];
  const float* bn_beta  = (const float*)d_in[6];
  const float* bn_mean  = (const float*)d_in[7];
  const float* bn_var   = (const float*)d_in[8];
  const int* edge_index = (const int*)d_in[9];
  float* out = (float*)d_out;

  char* ws = (char*)d_ws;
  float* wa   = (float*)ws;            // 4 KB
  int* iOff_g = (int*)(ws + 4096);
  int* iSrc_g = (int*)(ws + 4608);
  int* oOff_g = (int*)(ws + 6144);
  int* oDst_g = (int*)(ws + 6656);
  float* a_ws = (float*)(ws + 16384);                             // 8 MB [b][n][j][t]
  unsigned short* xs = (unsigned short*)(ws + 16384 + (size_t)8 * 1024 * 1024);  // 64 MB bf16 [b][tc][c][n][t16]

  setup_kernel<<<1, 256, 0, stream>>>(W, att_src, att_dst, edge_index, wa,
                                      iOff_g, iSrc_g, oOff_g, oDst_g);
  proj_kernel<<<1024, 256, 0, stream>>>(x, wa, a_ws, xs);
  agg_kernel<<<256, 512, 0, stream>>>(xs, a_ws, W, iOff_g, iSrc_g, oOff_g, oDst_g,
                                      bias, bn_gamma, bn_beta, bn_mean, bn_var,
                                      out);
}